// Round 17
// baseline (158.156 us; speedup 1.0000x reference)
//
#include <hip/hip_runtime.h>
#include <hip/hip_bf16.h>

// GraphSAGE 2-layer f32->bf16-hybrid (R17 = R16 + scatter micro-fixes):
//   k_init: edge-dtype detect + padded-cursor init (replaces memset)
//   mega1: [scatter: padded cursors (64B/line), nt stores] ∥ [mm1 MFMA]
//   k_bfinal: per-bucket LDS counting-sort -> rs/re + adj (in-place)
//   agg1mm2: 16 nodes/block, 4 parallel nodes/wave gather + fused MFMA -> zs
//   agg2: 8 nodes/wave concurrent: out = mean_src(zs[:,:32]) + zs[:,32:]

#define CHUNK 2048
#define BSHIFT 7
#define BCAP  2048        // avg 1536 edges/bucket, +6 sigma safe
#define CSTRIDE 16        // gcursor padded: 1 cursor per 64B line

typedef __attribute__((ext_vector_type(8))) short bf8;
typedef __attribute__((ext_vector_type(4))) float f4;

__device__ __forceinline__ unsigned short f2b(float f) {   // RNE f32->bf16
    unsigned u = __float_as_uint(f);
    u += 0x7FFF + ((u >> 16) & 1);
    return (unsigned short)(u >> 16);
}
__device__ __forceinline__ float blo(unsigned u) { return __uint_as_float(u << 16); }
__device__ __forceinline__ float bhi(unsigned u) { return __uint_as_float(u & 0xFFFF0000u); }

__device__ __forceinline__ bf8 load8f(const float* __restrict__ p) {
    float4 u0 = *(const float4*)p, u1 = *(const float4*)(p + 4);
    bf8 r;
    r[0] = (short)f2b(u0.x); r[1] = (short)f2b(u0.y);
    r[2] = (short)f2b(u0.z); r[3] = (short)f2b(u0.w);
    r[4] = (short)f2b(u1.x); r[5] = (short)f2b(u1.y);
    r[6] = (short)f2b(u1.z); r[7] = (short)f2b(u1.w);
    return r;
}

__device__ __forceinline__ int edge_src(const int* ei, int E, int e, bool i64) {
    return i64 ? ei[2 * e] : ei[e];
}
__device__ __forceinline__ int edge_dst(const int* ei, int E, int e, bool i64) {
    return i64 ? ei[2 * E + 2 * e] : ei[E + e];
}

// ---- k_init: detect edge dtype (block 0) + init padded cursors ----
__global__ __launch_bounds__(256) void k_init(const int* __restrict__ ei,
                                              int* __restrict__ flag,
                                              int* __restrict__ gcursor, int nbuck) {
    int t = blockIdx.x * 256 + threadIdx.x;
    if (blockIdx.x == 0) {
        if (threadIdx.x == 0) *flag = 0;
        __syncthreads();
        int v = ei[2 * threadIdx.x + 1];
        if (v != 0) atomicOr(flag, 1);   // 1 -> int32 layout, 0 -> int64
    }
    for (int b = t; b < nbuck; b += gridDim.x * 256) gcursor[b * CSTRIDE] = 0;
}

// ---- mega1: blocks [0,nwg) = edge scatter; [nwg, nwg+nb64) = mm1 ----
__global__ __launch_bounds__(256) void mega1(
        const int* __restrict__ ei, int E, const int* __restrict__ flag,
        int* __restrict__ gcursor,
        int* __restrict__ bucketed, int nbuck, int nwg,
        const float* __restrict__ x,
        const float* __restrict__ Wl1, const float* __restrict__ Wr1,
        const float* __restrict__ b1,
        unsigned short* __restrict__ P1b, unsigned short* __restrict__ Hb, int n) {
    __shared__ int lhist[1024];
    __shared__ int wgbase[1024];
    int t = threadIdx.x;
    if ((int)blockIdx.x < nwg) {
        // ---------- scatter ----------
#pragma unroll
        for (int i = 0; i < 4; ++i) lhist[t + 256 * i] = 0;
        __syncthreads();
        bool i64 = (flag[0] == 0);
        int base = blockIdx.x * CHUNK;
        int p[CHUNK / 256];
        int bk[CHUNK / 256];
#pragma unroll
        for (int i = 0; i < CHUNK / 256; ++i) {
            int e = base + i * 256 + t;
            if (e < E) {
                int s = edge_src(ei, E, e, i64);
                int d = edge_dst(ei, E, e, i64);
                p[i] = s | ((d & 127) << 24);
                bk[i] = d >> BSHIFT;
                atomicAdd(&lhist[bk[i]], 1);
            } else {
                bk[i] = -1;
            }
        }
        __syncthreads();
        for (int b = t; b < nbuck; b += 256) {
            int c = lhist[b];
            wgbase[b] = c ? atomicAdd(&gcursor[b * CSTRIDE], c) : 0;  // padded cursor
            lhist[b] = 0;
        }
        __syncthreads();
#pragma unroll
        for (int i = 0; i < CHUNK / 256; ++i) {
            if (bk[i] >= 0) {
                int r = atomicAdd(&lhist[bk[i]], 1);
                int off = wgbase[bk[i]] + r;
                if (off < BCAP)
                    __builtin_nontemporal_store(p[i],
                        &bucketed[(size_t)bk[i] * BCAP + off]);
            }
        }
    } else {
        // ---------- mm1: [P1b | Hb] = bf16(x) @ [Wl1 | Wr1] ----------
        int mb = blockIdx.x - nwg;
        int lane = t & 63, w = t >> 6;
        int rb = mb * 64;
        int r15 = lane & 15, kg = lane >> 4;
        bf8 a[4][2];
#pragma unroll
        for (int rt = 0; rt < 4; ++rt) {
            int row = rb + rt * 16 + r15; if (row >= n) row = n - 1;
            const float* ap = x + (size_t)row * 64 + kg * 8;
            a[rt][0] = load8f(ap);
            a[rt][1] = load8f(ap + 32);
        }
        bf8 b[2][2];
#pragma unroll
        for (int ct2 = 0; ct2 < 2; ++ct2) {
            int c = (w * 2 + ct2) * 16 + r15;
#pragma unroll
            for (int ks = 0; ks < 2; ++ks) {
                bf8 bv;
#pragma unroll
                for (int j = 0; j < 8; ++j) {
                    int k = ks * 32 + kg * 8 + j;
                    float wv = (c < 64) ? Wl1[k * 64 + c] : Wr1[k * 64 + (c - 64)];
                    bv[j] = (short)f2b(wv);
                }
                b[ct2][ks] = bv;
            }
        }
        f4 acc[4][2] = {};
#pragma unroll
        for (int rt = 0; rt < 4; ++rt)
#pragma unroll
            for (int ct2 = 0; ct2 < 2; ++ct2)
#pragma unroll
                for (int ks = 0; ks < 2; ++ks)
                    acc[rt][ct2] = __builtin_amdgcn_mfma_f32_16x16x32_bf16(
                        a[rt][ks], b[ct2][ks], acc[rt][ct2], 0, 0, 0);
#pragma unroll
        for (int ct2 = 0; ct2 < 2; ++ct2) {
            int col = (w * 2 + ct2) * 16 + r15;
            bool isH = col >= 64;
            float bias = isH ? b1[col - 64] : 0.f;
#pragma unroll
            for (int rt = 0; rt < 4; ++rt) {
                int row0 = rb + rt * 16 + kg * 4;
#pragma unroll
                for (int reg = 0; reg < 4; ++reg) {
                    int row = row0 + reg;
                    if (row < n) {
                        float val = acc[rt][ct2][reg];
                        if (isH) Hb[(size_t)row * 64 + (col - 64)] = f2b(val + bias);
                        else     P1b[(size_t)row * 64 + col] = f2b(val);
                    }
                }
            }
        }
    }
}

// ---- per-bucket finalize: LDS rank+scan -> rs/re + adj (in-place over bucketed) ----
__global__ __launch_bounds__(256) void k_bfinal(
        const int* __restrict__ bucketed, const int* __restrict__ gcursor,
        int* __restrict__ rs, int* __restrict__ re,
        int* __restrict__ adj, int n) {
    __shared__ int ledge[BCAP];
    __shared__ unsigned short lrank[BCAP];
    __shared__ int ldeg[128];
    __shared__ int lstart[257];
    int t = threadIdx.x, b = blockIdx.x;
    int start = b * BCAP;
    int cnt = gcursor[b * CSTRIDE];
    if (cnt > BCAP) cnt = BCAP;
    for (int i = t; i < cnt; i += 256) ledge[i] = bucketed[start + i];
    if (t < 128) ldeg[t] = 0;
    __syncthreads();
    for (int i = t; i < cnt; i += 256) {
        int dl = ((unsigned)ledge[i]) >> 24;
        lrank[i] = (unsigned short)atomicAdd(&ldeg[dl], 1);
    }
    __syncthreads();
    int v = (t < 128) ? ldeg[t] : 0;
    lstart[t + 1] = v;
    if (t == 0) lstart[0] = 0;
    __syncthreads();
    for (int off = 1; off < 256; off <<= 1) {
        int add = (t + 1 > off) ? lstart[t + 1 - off] : 0;
        __syncthreads();
        lstart[t + 1] += add;
        __syncthreads();
    }
    int node = b * 128 + t;
    if (t < 128 && node < n) {
        rs[node] = start + lstart[t];
        re[node] = start + lstart[t] + ldeg[t];
    }
    for (int i = t; i < cnt; i += 256) {   // all reads of bucketed done (LDS copy)
        int p = ledge[i];
        int dl = ((unsigned)p) >> 24;
        adj[start + lstart[dl] + lrank[i]] = p & 0xFFFFFF;
    }
}

// ---- agg1mm2: block = 16 nodes (4 waves x 4 parallel nodes/wave).
//      h = relu(mean_src(P1b)+Hb) -> LDS -> per-wave MFMA -> zs = [z2|S2] bf16 ----
__global__ __launch_bounds__(256) void agg1mm2(
        const unsigned short* __restrict__ P1b, const int* __restrict__ rs,
        const int* __restrict__ re, const int* __restrict__ adj,
        const unsigned short* __restrict__ Hb,
        const float* __restrict__ Wl2, const float* __restrict__ Wr2,
        const float* __restrict__ b2, unsigned short* __restrict__ zs, int n) {
    __shared__ unsigned short hl[16][72];   // 144B row stride, 16B-aligned
    int w = threadIdx.x >> 6, lane = threadIdx.x & 63;
    int g  = lane >> 4;            // node slot 0..3
    int e2 = (lane >> 3) & 1;      // edge sub-slot 0..1
    int f8 = lane & 7;             // feature slot (16B of the 128B row)
    int vbase = blockIdx.x * 16;
    int lr = w * 4 + g;            // local row 0..15
    int v = vbase + lr;
    bool valid = v < n;
    int vc = valid ? v : (n - 1);
    int s0 = rs[vc], s1 = re[vc], last = s1 - 1;
    float acc[8] = {0.f, 0.f, 0.f, 0.f, 0.f, 0.f, 0.f, 0.f};
    const uint4* P4 = (const uint4*)P1b;
    for (int e = s0; e < s1; e += 16) {
#pragma unroll
        for (int u = 0; u < 8; ++u) {          // 8 independent rounds: 16 edges/node
            int ei = e + u * 2 + e2;
            int ec = ei > last ? last : ei;
            int src = adj[ec];
            uint4 q = P4[(size_t)src * 8 + f8];
            float m = (ei <= last) ? 1.f : 0.f;
            acc[0] = fmaf(m, blo(q.x), acc[0]);
            acc[1] = fmaf(m, bhi(q.x), acc[1]);
            acc[2] = fmaf(m, blo(q.y), acc[2]);
            acc[3] = fmaf(m, bhi(q.y), acc[3]);
            acc[4] = fmaf(m, blo(q.z), acc[4]);
            acc[5] = fmaf(m, bhi(q.z), acc[5]);
            acc[6] = fmaf(m, blo(q.w), acc[6]);
            acc[7] = fmaf(m, bhi(q.w), acc[7]);
        }
    }
#pragma unroll
    for (int i = 0; i < 8; ++i) acc[i] += __shfl_xor(acc[i], 8);   // combine e2 pair
    if (e2 == 0) {
        uint4 o = make_uint4(0, 0, 0, 0);
        if (valid) {
            float inv = 1.f / fmaxf((float)(s1 - s0), 1.f);
            uint4 u = ((const uint4*)(Hb + (size_t)v * 64))[f8];
            float hv[8] = {blo(u.x), bhi(u.x), blo(u.y), bhi(u.y),
                           blo(u.z), bhi(u.z), blo(u.w), bhi(u.w)};
            float g0 = fmaxf(fmaf(acc[0], inv, hv[0]), 0.f);
            float g1 = fmaxf(fmaf(acc[1], inv, hv[1]), 0.f);
            float g2 = fmaxf(fmaf(acc[2], inv, hv[2]), 0.f);
            float g3 = fmaxf(fmaf(acc[3], inv, hv[3]), 0.f);
            float g4 = fmaxf(fmaf(acc[4], inv, hv[4]), 0.f);
            float g5 = fmaxf(fmaf(acc[5], inv, hv[5]), 0.f);
            float g6 = fmaxf(fmaf(acc[6], inv, hv[6]), 0.f);
            float g7 = fmaxf(fmaf(acc[7], inv, hv[7]), 0.f);
            o.x = f2b(g0) | ((unsigned)f2b(g1) << 16);
            o.y = f2b(g2) | ((unsigned)f2b(g3) << 16);
            o.z = f2b(g4) | ((unsigned)f2b(g5) << 16);
            o.w = f2b(g6) | ((unsigned)f2b(g7) << 16);
        }
        *(uint4*)&hl[lr][f8 * 8] = o;
    }
    __syncthreads();
    // ---- fused mm2: zs[16 x 64] = h @ [Wl2 | Wr2]; wave w -> cols w*16..+16 ----
    int r15 = lane & 15, kg = lane >> 4;
    bf8 a2[2];
#pragma unroll
    for (int ks = 0; ks < 2; ++ks)
        a2[ks] = *(const bf8*)&hl[r15][ks * 32 + kg * 8];
    int c = w * 16 + r15;
    bf8 b2f[2];
#pragma unroll
    for (int ks = 0; ks < 2; ++ks) {
        bf8 bv;
#pragma unroll
        for (int j = 0; j < 8; ++j) {
            int k = ks * 32 + kg * 8 + j;
            float wv = (c < 32) ? Wl2[k * 32 + c] : Wr2[k * 32 + (c - 32)];
            bv[j] = (short)f2b(wv);
        }
        b2f[ks] = bv;
    }
    f4 oacc = {};
#pragma unroll
    for (int ks = 0; ks < 2; ++ks)
        oacc = __builtin_amdgcn_mfma_f32_16x16x32_bf16(a2[ks], b2f[ks], oacc, 0, 0, 0);
    bool isS = c >= 32;
    float bias = isS ? b2[c - 32] : 0.f;
#pragma unroll
    for (int reg = 0; reg < 4; ++reg) {
        int row = vbase + kg * 4 + reg;
        if (row < n) zs[(size_t)row * 64 + c] = f2b(oacc[reg] + bias);
    }
}

// ---- agg2: 8 nodes/wave concurrent. out = mean_src(zs[:,:32]) + zs[:,32:] ----
__global__ __launch_bounds__(256) void agg2(
        const unsigned short* __restrict__ zs, const int* __restrict__ rs,
        const int* __restrict__ re, const int* __restrict__ adj,
        float* __restrict__ out, int n) {
    int w = threadIdx.x >> 6, lane = threadIdx.x & 63;
    int g  = lane >> 3;            // node slot 0..7
    int e2 = (lane >> 2) & 1;      // edge sub-slot 0..1
    int f4c = lane & 3;            // feature slot (16B of the 64B z2 row)
    int v = blockIdx.x * 32 + w * 8 + g;
    bool valid = v < n;
    int vc = valid ? v : (n - 1);
    int s0 = rs[vc], s1 = re[vc], last = s1 - 1;
    float acc[8] = {0.f, 0.f, 0.f, 0.f, 0.f, 0.f, 0.f, 0.f};
    const uint4* Z4 = (const uint4*)zs;
    for (int e = s0; e < s1; e += 16) {
#pragma unroll
        for (int u = 0; u < 8; ++u) {          // 8 independent rounds: 16 edges/node
            int ei = e + u * 2 + e2;
            int ec = ei > last ? last : ei;
            int src = adj[ec];
            uint4 q = Z4[(size_t)src * 8 + f4c];   // z2 = first 4 uint4 of the row
            float m = (ei <= last) ? 1.f : 0.f;
            acc[0] = fmaf(m, blo(q.x), acc[0]);
            acc[1] = fmaf(m, bhi(q.x), acc[1]);
            acc[2] = fmaf(m, blo(q.y), acc[2]);
            acc[3] = fmaf(m, bhi(q.y), acc[3]);
            acc[4] = fmaf(m, blo(q.z), acc[4]);
            acc[5] = fmaf(m, bhi(q.z), acc[5]);
            acc[6] = fmaf(m, blo(q.w), acc[6]);
            acc[7] = fmaf(m, bhi(q.w), acc[7]);
        }
    }
#pragma unroll
    for (int i = 0; i < 8; ++i) acc[i] += __shfl_xor(acc[i], 4);   // combine e2 pair
    if (e2 == 0 && valid) {
        float inv = 1.f / fmaxf((float)(s1 - s0), 1.f);
        uint4 u0 = ((const uint4*)(zs + (size_t)v * 64 + 32))[f4c];   // S2 slice
        float sv[8] = {blo(u0.x), bhi(u0.x), blo(u0.y), bhi(u0.y),
                       blo(u0.z), bhi(u0.z), blo(u0.w), bhi(u0.w)};
        float4 o0, o1;
        o0.x = fmaf(acc[0], inv, sv[0]);
        o0.y = fmaf(acc[1], inv, sv[1]);
        o0.z = fmaf(acc[2], inv, sv[2]);
        o0.w = fmaf(acc[3], inv, sv[3]);
        o1.x = fmaf(acc[4], inv, sv[4]);
        o1.y = fmaf(acc[5], inv, sv[5]);
        o1.z = fmaf(acc[6], inv, sv[6]);
        o1.w = fmaf(acc[7], inv, sv[7]);
        ((float4*)(out + (size_t)v * 32))[f4c * 2] = o0;
        ((float4*)(out + (size_t)v * 32))[f4c * 2 + 1] = o1;
    }
}

extern "C" void kernel_launch(void* const* d_in, const int* in_sizes, int n_in,
                              void* d_out, int out_size, void* d_ws, size_t ws_size,
                              hipStream_t stream) {
    const float* x   = (const float*)d_in[0];
    const int*   ei  = (const int*)d_in[1];
    const float* Wl1 = (const float*)d_in[2];
    const float* Wr1 = (const float*)d_in[3];
    const float* b1  = (const float*)d_in[4];
    const float* Wl2 = (const float*)d_in[5];
    const float* Wr2 = (const float*)d_in[6];
    const float* b2  = (const float*)d_in[7];

    int N = in_sizes[0] / 64;
    int E = in_sizes[1] / 2;
    int nbuck = (N + 127) >> BSHIFT;       // 782 for N=100000

    char* ws = (char*)d_ws;
    size_t o = 0;
    auto alloc = [&](size_t bytes) -> char* {
        char* p = ws + o;
        o = (o + bytes + 255) & ~(size_t)255;
        return p;
    };
    int* flag     = (int*)alloc(4);
    int* gcursor  = (int*)alloc((size_t)nbuck * CSTRIDE * 4);  // 64B per cursor
    int* rs       = (int*)alloc((size_t)N * 4);
    int* re       = (int*)alloc((size_t)N * 4);
    int* bucketed = (int*)alloc((size_t)nbuck * BCAP * 4);     // adj aliases this
    unsigned short* P1b = (unsigned short*)alloc((size_t)N * 64 * 2);
    unsigned short* Hb  = (unsigned short*)alloc((size_t)N * 64 * 2);
    unsigned short* zs  = (unsigned short*)alloc((size_t)N * 64 * 2);
    int* adj = bucketed;                        // rewritten in-place by k_bfinal

    int nwg  = (E + CHUNK - 1) / CHUNK;
    int nb64 = (N + 63) / 64;
    int nb16 = (N + 15) / 16;
    int nb32 = (N + 31) / 32;
    k_init<<<16, 256, 0, stream>>>(ei, flag, gcursor, nbuck);
    mega1<<<nwg + nb64, 256, 0, stream>>>(ei, E, flag, gcursor, bucketed, nbuck, nwg,
                                          x, Wl1, Wr1, b1, P1b, Hb, N);
    k_bfinal<<<nbuck, 256, 0, stream>>>(bucketed, gcursor, rs, re, adj, N);
    agg1mm2<<<nb16, 256, 0, stream>>>(P1b, rs, re, adj, Hb, Wl2, Wr2, b2, zs, N);
    agg2<<<nb32, 256, 0, stream>>>(zs, rs, re, adj, (float*)d_out, N);
}

// Round 18
// 128.506 us; speedup vs baseline: 1.2307x; 1.2307x over previous
//
#include <hip/hip_runtime.h>
#include <hip/hip_bf16.h>

// GraphSAGE 2-layer f32->bf16-hybrid (R18 = exact revert to R16, the best
// measured config: 129.0 us). R17's nt-store + padded-cursor "fixes" doubled
// scatter WRITE_SIZE (43->96 MB) and regressed to 158 us — reverted.
//   memset cursors
//   mega1: [scatter edges into 128-node buckets] ∥ [mm1: P1b,Hb = bf16(x)@[Wl1|Wr1]]
//   k_bfinal: per-bucket LDS counting-sort -> rs/re + adj (in-place)
//   agg1mm2: block = 16 nodes (4 waves x 4 concurrent nodes):
//            h = relu(mean_src(P1b)+Hb) -> LDS [16][72] -> one MFMA pair/wave
//            -> zs = [h@Wl2 | h@Wr2+b2] bf16
//   agg2: 8 nodes/wave concurrent: out = mean_src(zs[:,:32]) + zs[:,32:]

#define CHUNK 2048
#define BSHIFT 7
#define BCAP  2048        // avg 1536 edges/bucket, +6 sigma safe

typedef __attribute__((ext_vector_type(8))) short bf8;
typedef __attribute__((ext_vector_type(4))) float f4;

__device__ __forceinline__ unsigned short f2b(float f) {   // RNE f32->bf16
    unsigned u = __float_as_uint(f);
    u += 0x7FFF + ((u >> 16) & 1);
    return (unsigned short)(u >> 16);
}
__device__ __forceinline__ float blo(unsigned u) { return __uint_as_float(u << 16); }
__device__ __forceinline__ float bhi(unsigned u) { return __uint_as_float(u & 0xFFFF0000u); }

__device__ __forceinline__ bf8 load8f(const float* __restrict__ p) {
    float4 u0 = *(const float4*)p, u1 = *(const float4*)(p + 4);
    bf8 r;
    r[0] = (short)f2b(u0.x); r[1] = (short)f2b(u0.y);
    r[2] = (short)f2b(u0.z); r[3] = (short)f2b(u0.w);
    r[4] = (short)f2b(u1.x); r[5] = (short)f2b(u1.y);
    r[6] = (short)f2b(u1.z); r[7] = (short)f2b(u1.w);
    return r;
}

__device__ __forceinline__ int edge_src(const int* ei, int E, int e, bool i64) {
    return i64 ? ei[2 * e] : ei[e];
}
__device__ __forceinline__ int edge_dst(const int* ei, int E, int e, bool i64) {
    return i64 ? ei[2 * E + 2 * e] : ei[E + e];
}

// ---- mega1: blocks [0,nwg) = edge scatter; [nwg, nwg+nb64) = mm1 ----
__global__ __launch_bounds__(256) void mega1(
        const int* __restrict__ ei, int E, int* __restrict__ gcursor,
        int* __restrict__ bucketed, int nbuck, int nwg,
        const float* __restrict__ x,
        const float* __restrict__ Wl1, const float* __restrict__ Wr1,
        const float* __restrict__ b1,
        unsigned short* __restrict__ P1b, unsigned short* __restrict__ Hb, int n) {
    __shared__ int lhist[1024];
    __shared__ int wgbase[1024];
    __shared__ int sflag;
    int t = threadIdx.x;
    if ((int)blockIdx.x < nwg) {
        // ---------- scatter ----------
        if (t == 0) sflag = 0;
#pragma unroll
        for (int i = 0; i < 4; ++i) lhist[t + 256 * i] = 0;
        __syncthreads();
        int base = blockIdx.x * CHUNK;
        int myor = 0;
#pragma unroll
        for (int i = 0; i < CHUNK / 256; ++i) {
            int e = base + i * 256 + t;
            if (e < E) myor |= ei[2 * e + 1];   // int64 layout: high words all 0
        }
        if (myor) atomicOr(&sflag, 1);
        __syncthreads();
        bool i64 = (sflag == 0);
        int p[CHUNK / 256];
        int bk[CHUNK / 256];
#pragma unroll
        for (int i = 0; i < CHUNK / 256; ++i) {
            int e = base + i * 256 + t;
            if (e < E) {
                int s = edge_src(ei, E, e, i64);
                int d = edge_dst(ei, E, e, i64);
                p[i] = s | ((d & 127) << 24);
                bk[i] = d >> BSHIFT;
                atomicAdd(&lhist[bk[i]], 1);
            } else {
                bk[i] = -1;
            }
        }
        __syncthreads();
        for (int b = t; b < nbuck; b += 256) {
            int c = lhist[b];
            wgbase[b] = c ? atomicAdd(&gcursor[b], c) : 0;  // relative offset
            lhist[b] = 0;
        }
        __syncthreads();
#pragma unroll
        for (int i = 0; i < CHUNK / 256; ++i) {
            if (bk[i] >= 0) {
                int r = atomicAdd(&lhist[bk[i]], 1);
                int off = wgbase[bk[i]] + r;
                if (off < BCAP) bucketed[(size_t)bk[i] * BCAP + off] = p[i];
            }
        }
    } else {
        // ---------- mm1: [P1b | Hb] = bf16(x) @ [Wl1 | Wr1] ----------
        int mb = blockIdx.x - nwg;
        int lane = t & 63, w = t >> 6;
        int rb = mb * 64;
        int r15 = lane & 15, kg = lane >> 4;
        bf8 a[4][2];
#pragma unroll
        for (int rt = 0; rt < 4; ++rt) {
            int row = rb + rt * 16 + r15; if (row >= n) row = n - 1;
            const float* ap = x + (size_t)row * 64 + kg * 8;
            a[rt][0] = load8f(ap);
            a[rt][1] = load8f(ap + 32);
        }
        bf8 b[2][2];
#pragma unroll
        for (int ct2 = 0; ct2 < 2; ++ct2) {
            int c = (w * 2 + ct2) * 16 + r15;
#pragma unroll
            for (int ks = 0; ks < 2; ++ks) {
                bf8 bv;
#pragma unroll
                for (int j = 0; j < 8; ++j) {
                    int k = ks * 32 + kg * 8 + j;
                    float wv = (c < 64) ? Wl1[k * 64 + c] : Wr1[k * 64 + (c - 64)];
                    bv[j] = (short)f2b(wv);
                }
                b[ct2][ks] = bv;
            }
        }
        f4 acc[4][2] = {};
#pragma unroll
        for (int rt = 0; rt < 4; ++rt)
#pragma unroll
            for (int ct2 = 0; ct2 < 2; ++ct2)
#pragma unroll
                for (int ks = 0; ks < 2; ++ks)
                    acc[rt][ct2] = __builtin_amdgcn_mfma_f32_16x16x32_bf16(
                        a[rt][ks], b[ct2][ks], acc[rt][ct2], 0, 0, 0);
#pragma unroll
        for (int ct2 = 0; ct2 < 2; ++ct2) {
            int col = (w * 2 + ct2) * 16 + r15;
            bool isH = col >= 64;
            float bias = isH ? b1[col - 64] : 0.f;
#pragma unroll
            for (int rt = 0; rt < 4; ++rt) {
                int row0 = rb + rt * 16 + kg * 4;
#pragma unroll
                for (int reg = 0; reg < 4; ++reg) {
                    int row = row0 + reg;
                    if (row < n) {
                        float val = acc[rt][ct2][reg];
                        if (isH) Hb[(size_t)row * 64 + (col - 64)] = f2b(val + bias);
                        else     P1b[(size_t)row * 64 + col] = f2b(val);
                    }
                }
            }
        }
    }
}

// ---- per-bucket finalize: LDS rank+scan -> rs/re + adj (in-place over bucketed) ----
__global__ __launch_bounds__(256) void k_bfinal(
        const int* __restrict__ bucketed, const int* __restrict__ gcursor,
        int* __restrict__ rs, int* __restrict__ re,
        int* __restrict__ adj, int n) {
    __shared__ int ledge[BCAP];
    __shared__ unsigned short lrank[BCAP];
    __shared__ int ldeg[128];
    __shared__ int lstart[257];
    int t = threadIdx.x, b = blockIdx.x;
    int start = b * BCAP;
    int cnt = gcursor[b];
    if (cnt > BCAP) cnt = BCAP;
    for (int i = t; i < cnt; i += 256) ledge[i] = bucketed[start + i];
    if (t < 128) ldeg[t] = 0;
    __syncthreads();
    for (int i = t; i < cnt; i += 256) {
        int dl = ((unsigned)ledge[i]) >> 24;
        lrank[i] = (unsigned short)atomicAdd(&ldeg[dl], 1);
    }
    __syncthreads();
    int v = (t < 128) ? ldeg[t] : 0;
    lstart[t + 1] = v;
    if (t == 0) lstart[0] = 0;
    __syncthreads();
    for (int off = 1; off < 256; off <<= 1) {
        int add = (t + 1 > off) ? lstart[t + 1 - off] : 0;
        __syncthreads();
        lstart[t + 1] += add;
        __syncthreads();
    }
    int node = b * 128 + t;
    if (t < 128 && node < n) {
        rs[node] = start + lstart[t];
        re[node] = start + lstart[t] + ldeg[t];
    }
    for (int i = t; i < cnt; i += 256) {   // all reads of bucketed done (LDS copy)
        int p = ledge[i];
        int dl = ((unsigned)p) >> 24;
        adj[start + lstart[dl] + lrank[i]] = p & 0xFFFFFF;
    }
}

// ---- agg1mm2: block = 16 nodes (4 waves x 4 parallel nodes/wave).
//      h = relu(mean_src(P1b)+Hb) -> LDS -> per-wave MFMA -> zs = [z2|S2] bf16 ----
__global__ __launch_bounds__(256) void agg1mm2(
        const unsigned short* __restrict__ P1b, const int* __restrict__ rs,
        const int* __restrict__ re, const int* __restrict__ adj,
        const unsigned short* __restrict__ Hb,
        const float* __restrict__ Wl2, const float* __restrict__ Wr2,
        const float* __restrict__ b2, unsigned short* __restrict__ zs, int n) {
    __shared__ unsigned short hl[16][72];   // 144B row stride, 16B-aligned
    int w = threadIdx.x >> 6, lane = threadIdx.x & 63;
    int g  = lane >> 4;            // node slot 0..3
    int e2 = (lane >> 3) & 1;      // edge sub-slot 0..1
    int f8 = lane & 7;             // feature slot (16B of the 128B row)
    int vbase = blockIdx.x * 16;
    int lr = w * 4 + g;            // local row 0..15
    int v = vbase + lr;
    bool valid = v < n;
    int vc = valid ? v : (n - 1);
    int s0 = rs[vc], s1 = re[vc], last = s1 - 1;
    float acc[8] = {0.f, 0.f, 0.f, 0.f, 0.f, 0.f, 0.f, 0.f};
    const uint4* P4 = (const uint4*)P1b;
    for (int e = s0; e < s1; e += 16) {
#pragma unroll
        for (int u = 0; u < 8; ++u) {          // 8 independent rounds: 16 edges/node
            int ei = e + u * 2 + e2;
            int ec = ei > last ? last : ei;
            int src = adj[ec];
            uint4 q = P4[(size_t)src * 8 + f8];
            float m = (ei <= last) ? 1.f : 0.f;
            acc[0] = fmaf(m, blo(q.x), acc[0]);
            acc[1] = fmaf(m, bhi(q.x), acc[1]);
            acc[2] = fmaf(m, blo(q.y), acc[2]);
            acc[3] = fmaf(m, bhi(q.y), acc[3]);
            acc[4] = fmaf(m, blo(q.z), acc[4]);
            acc[5] = fmaf(m, bhi(q.z), acc[5]);
            acc[6] = fmaf(m, blo(q.w), acc[6]);
            acc[7] = fmaf(m, bhi(q.w), acc[7]);
        }
    }
#pragma unroll
    for (int i = 0; i < 8; ++i) acc[i] += __shfl_xor(acc[i], 8);   // combine e2 pair
    if (e2 == 0) {
        uint4 o = make_uint4(0, 0, 0, 0);
        if (valid) {
            float inv = 1.f / fmaxf((float)(s1 - s0), 1.f);
            uint4 u = ((const uint4*)(Hb + (size_t)v * 64))[f8];
            float hv[8] = {blo(u.x), bhi(u.x), blo(u.y), bhi(u.y),
                           blo(u.z), bhi(u.z), blo(u.w), bhi(u.w)};
            float g0 = fmaxf(fmaf(acc[0], inv, hv[0]), 0.f);
            float g1 = fmaxf(fmaf(acc[1], inv, hv[1]), 0.f);
            float g2 = fmaxf(fmaf(acc[2], inv, hv[2]), 0.f);
            float g3 = fmaxf(fmaf(acc[3], inv, hv[3]), 0.f);
            float g4 = fmaxf(fmaf(acc[4], inv, hv[4]), 0.f);
            float g5 = fmaxf(fmaf(acc[5], inv, hv[5]), 0.f);
            float g6 = fmaxf(fmaf(acc[6], inv, hv[6]), 0.f);
            float g7 = fmaxf(fmaf(acc[7], inv, hv[7]), 0.f);
            o.x = f2b(g0) | ((unsigned)f2b(g1) << 16);
            o.y = f2b(g2) | ((unsigned)f2b(g3) << 16);
            o.z = f2b(g4) | ((unsigned)f2b(g5) << 16);
            o.w = f2b(g6) | ((unsigned)f2b(g7) << 16);
        }
        *(uint4*)&hl[lr][f8 * 8] = o;
    }
    __syncthreads();
    // ---- fused mm2: zs[16 x 64] = h @ [Wl2 | Wr2]; wave w -> cols w*16..+16 ----
    int r15 = lane & 15, kg = lane >> 4;
    bf8 a2[2];
#pragma unroll
    for (int ks = 0; ks < 2; ++ks)
        a2[ks] = *(const bf8*)&hl[r15][ks * 32 + kg * 8];
    int c = w * 16 + r15;
    bf8 b2f[2];
#pragma unroll
    for (int ks = 0; ks < 2; ++ks) {
        bf8 bv;
#pragma unroll
        for (int j = 0; j < 8; ++j) {
            int k = ks * 32 + kg * 8 + j;
            float wv = (c < 32) ? Wl2[k * 32 + c] : Wr2[k * 32 + (c - 32)];
            bv[j] = (short)f2b(wv);
        }
        b2f[ks] = bv;
    }
    f4 oacc = {};
#pragma unroll
    for (int ks = 0; ks < 2; ++ks)
        oacc = __builtin_amdgcn_mfma_f32_16x16x32_bf16(a2[ks], b2f[ks], oacc, 0, 0, 0);
    bool isS = c >= 32;
    float bias = isS ? b2[c - 32] : 0.f;
#pragma unroll
    for (int reg = 0; reg < 4; ++reg) {
        int row = vbase + kg * 4 + reg;
        if (row < n) zs[(size_t)row * 64 + c] = f2b(oacc[reg] + bias);
    }
}

// ---- agg2: 8 nodes/wave concurrent. out = mean_src(zs[:,:32]) + zs[:,32:] ----
__global__ __launch_bounds__(256) void agg2(
        const unsigned short* __restrict__ zs, const int* __restrict__ rs,
        const int* __restrict__ re, const int* __restrict__ adj,
        float* __restrict__ out, int n) {
    int w = threadIdx.x >> 6, lane = threadIdx.x & 63;
    int g  = lane >> 3;            // node slot 0..7
    int e2 = (lane >> 2) & 1;      // edge sub-slot 0..1
    int f4c = lane & 3;            // feature slot (16B of the 64B z2 row)
    int v = blockIdx.x * 32 + w * 8 + g;
    bool valid = v < n;
    int vc = valid ? v : (n - 1);
    int s0 = rs[vc], s1 = re[vc], last = s1 - 1;
    float acc[8] = {0.f, 0.f, 0.f, 0.f, 0.f, 0.f, 0.f, 0.f};
    const uint4* Z4 = (const uint4*)zs;
    for (int e = s0; e < s1; e += 16) {
#pragma unroll
        for (int u = 0; u < 8; ++u) {          // 8 independent rounds: 16 edges/node
            int ei = e + u * 2 + e2;
            int ec = ei > last ? last : ei;
            int src = adj[ec];
            uint4 q = Z4[(size_t)src * 8 + f4c];   // z2 = first 4 uint4 of the row
            float m = (ei <= last) ? 1.f : 0.f;
            acc[0] = fmaf(m, blo(q.x), acc[0]);
            acc[1] = fmaf(m, bhi(q.x), acc[1]);
            acc[2] = fmaf(m, blo(q.y), acc[2]);
            acc[3] = fmaf(m, bhi(q.y), acc[3]);
            acc[4] = fmaf(m, blo(q.z), acc[4]);
            acc[5] = fmaf(m, bhi(q.z), acc[5]);
            acc[6] = fmaf(m, blo(q.w), acc[6]);
            acc[7] = fmaf(m, bhi(q.w), acc[7]);
        }
    }
#pragma unroll
    for (int i = 0; i < 8; ++i) acc[i] += __shfl_xor(acc[i], 4);   // combine e2 pair
    if (e2 == 0 && valid) {
        float inv = 1.f / fmaxf((float)(s1 - s0), 1.f);
        uint4 u0 = ((const uint4*)(zs + (size_t)v * 64 + 32))[f4c];   // S2 slice
        float sv[8] = {blo(u0.x), bhi(u0.x), blo(u0.y), bhi(u0.y),
                       blo(u0.z), bhi(u0.z), blo(u0.w), bhi(u0.w)};
        float4 o0, o1;
        o0.x = fmaf(acc[0], inv, sv[0]);
        o0.y = fmaf(acc[1], inv, sv[1]);
        o0.z = fmaf(acc[2], inv, sv[2]);
        o0.w = fmaf(acc[3], inv, sv[3]);
        o1.x = fmaf(acc[4], inv, sv[4]);
        o1.y = fmaf(acc[5], inv, sv[5]);
        o1.z = fmaf(acc[6], inv, sv[6]);
        o1.w = fmaf(acc[7], inv, sv[7]);
        ((float4*)(out + (size_t)v * 32))[f4c * 2] = o0;
        ((float4*)(out + (size_t)v * 32))[f4c * 2 + 1] = o1;
    }
}

extern "C" void kernel_launch(void* const* d_in, const int* in_sizes, int n_in,
                              void* d_out, int out_size, void* d_ws, size_t ws_size,
                              hipStream_t stream) {
    const float* x   = (const float*)d_in[0];
    const int*   ei  = (const int*)d_in[1];
    const float* Wl1 = (const float*)d_in[2];
    const float* Wr1 = (const float*)d_in[3];
    const float* b1  = (const float*)d_in[4];
    const float* Wl2 = (const float*)d_in[5];
    const float* Wr2 = (const float*)d_in[6];
    const float* b2  = (const float*)d_in[7];

    int N = in_sizes[0] / 64;
    int E = in_sizes[1] / 2;
    int nbuck = (N + 127) >> BSHIFT;       // 782 for N=100000

    char* ws = (char*)d_ws;
    size_t o = 0;
    auto alloc = [&](size_t bytes) -> char* {
        char* p = ws + o;
        o = (o + bytes + 255) & ~(size_t)255;
        return p;
    };
    int* gcursor  = (int*)alloc((size_t)nbuck * 4);
    int* rs       = (int*)alloc((size_t)N * 4);
    int* re       = (int*)alloc((size_t)N * 4);
    int* bucketed = (int*)alloc((size_t)nbuck * BCAP * 4);   // adj aliases this
    unsigned short* P1b = (unsigned short*)alloc((size_t)N * 64 * 2);
    unsigned short* Hb  = (unsigned short*)alloc((size_t)N * 64 * 2);
    unsigned short* zs  = (unsigned short*)alloc((size_t)N * 64 * 2);
    int* adj = bucketed;                        // rewritten in-place by k_bfinal

    hipMemsetAsync(gcursor, 0, (size_t)nbuck * 4, stream);

    int nwg  = (E + CHUNK - 1) / CHUNK;
    int nb64 = (N + 63) / 64;
    int nb16 = (N + 15) / 16;
    int nb32 = (N + 31) / 32;
    mega1<<<nwg + nb64, 256, 0, stream>>>(ei, E, gcursor, bucketed, nbuck, nwg,
                                          x, Wl1, Wr1, b1, P1b, Hb, N);
    k_bfinal<<<nbuck, 256, 0, stream>>>(bucketed, gcursor, rs, re, adj, N);
    agg1mm2<<<nb16, 256, 0, stream>>>(P1b, rs, re, adj, Hb, Wl2, Wr2, b2, zs, N);
    agg2<<<nb32, 256, 0, stream>>>(zs, rs, re, adj, (float*)d_out, N);
}